// Round 9
// baseline (150.362 us; speedup 1.0000x reference)
//
#include <hip/hip_runtime.h>
#include <math.h>

#define BATCH 16384
#define NSETS 1024
#define ALPHA 0.001f
#define BETA  0.001f

// R19: masses frozen at R13-verbatim (proven 51.4 us; R15/R17/R18 proved it
// invariant to occupancy, LDS size, drain semantics, and epilogue removal --
// 5 attacks exhausted). This round attacks the UNMEASURED kernel: bce
// (~30-40 us by e2e triangulation vs ~13 us streaming floor, always below
// the top-5 cutoff). Theory: latency-bound blocks + ragged 1.6-round grid
// (2112 blocks at ~5/CU from VGPR ~90 with 16 float4 live).
// Fix: 4 rows/block -> 4160 blocks (moeb blocks FIRST, ids 0..63), data regs
// halve (P[4]+T[4]=32 VGPR -> ~8 blocks/CU, thread-cap) -> 2.0 balanced
// scheduling rounds, 2x shorter blocks, ~60% more loads in flight per CU.
// Per-element math unchanged (clip, cvt_pk fp8, product-of-4 logf).
#define BM 128
#define BN 128
#define BK 128
#define NSTRIPE (BATCH / BM)            // 128 m-stripes
#define NBLK_N  (NSETS / BN)            // 8 n-blocks per stripe
#define GEMM_BLOCKS (NSTRIPE * NBLK_N)  // 1024
#define KITER (NSETS / BK)              // 8
#define BCE_BLOCKS 4096                 // 4 rows each
#define K1_GRID (64 + BCE_BLOCKS)       // moeb first, then bce

typedef __attribute__((ext_vector_type(4))) float f32x4;
typedef __attribute__((ext_vector_type(2))) long s64x2;

// ws float-index layout (R10/R13 layout):
//   [0] mr_sum  [1] global counter (uint)  [2] ms_sum  [3] pad  (zeroed k1)
//   [4 .. 4+4096)            bce per-block partials (write-once, 4096 blocks)
//   [8192 .. 8192+16384)     row sums (atomics; zeroed by k1 bce blocks)
//   [24576 .. 24576+128)     per-stripe counters (uint; zeroed by k1 block 65)
//   [28672 .. 28672+65536)   c_part[64][1024] moebius colsum partials (w-once)
// ws byte layout:
//   [393216 ..)              pred_fp8 (16.8 MB, k-interleaved)
//   [393216 + 16777216 ..)   moeb_fp8 (1 MB, k-interleaved)
#define BCEP_OFF   4
#define ROWSUM_OFF 8192
#define STRIPE_OFF 24576
#define CPART_OFF  28672
#define WS_PREDF8_OFF 393216
#define WS_MOEBF8_OFF (393216 + BATCH * NSETS)

__device__ __forceinline__ void gld16(const void* g, void* l) {
    __builtin_amdgcn_global_load_lds(
        (const __attribute__((address_space(1))) unsigned int*)g,
        (__attribute__((address_space(3))) unsigned int*)l, 16, 0, 0);
}

// 4 fp32 -> 4 fp8 e4m3 (OCP) packed in an int, HW converter
__device__ __forceinline__ int pk_fp8x4(float a, float b, float c, float d) {
    int v = 0;
    v = __builtin_amdgcn_cvt_pk_fp8_f32(a, b, v, 0);   // low word
    v = __builtin_amdgcn_cvt_pk_fp8_f32(c, d, v, 1);   // high word
    return v;
}

// dword-in-row permutation implementing the 8B k-chunk interleave within each
// 128B k-group: chunk o -> (o&8) | ((o&3)<<1) | ((o>>2)&1).  With this layout
// a lane's MFMA chunks (8H+q, 8H+q+4) are ADJACENT -> b128 fragment reads.
__device__ __forceinline__ int permute_dword(int d) {
    const int g = d >> 5;          // 128B group (32 dwords)
    const int w = d & 31;
    const int o = w >> 1;          // 8B chunk 0..15
    const int p = w & 1;
    const int n = (o & 8) | ((o & 3) << 1) | ((o >> 2) & 1);
    return (g << 5) | (n << 1) | p;
}

// relaxed agent-scope load: bypasses (possibly stale) L1/L2, no cache inval
__device__ __forceinline__ float coh_load(const float* p) {
    return __hip_atomic_load(p, __ATOMIC_RELAXED, __HIP_MEMORY_SCOPE_AGENT);
}

__device__ __forceinline__ float block_reduce_sum(float v, float* sm) {
    #pragma unroll
    for (int off = 32; off > 0; off >>= 1) v += __shfl_down(v, off, 64);
    const int lane = threadIdx.x & 63;
    const int wid  = threadIdx.x >> 6;
    if (lane == 0) sm[wid] = v;
    __syncthreads();
    const int nw = blockDim.x >> 6;
    v = (threadIdx.x < nw) ? sm[threadIdx.x] : 0.0f;
    if (wid == 0) {
        #pragma unroll
        for (int off = 32; off > 0; off >>= 1) v += __shfl_down(v, off, 64);
    }
    return v;  // valid in thread 0
}

// -------- k1: blocks 0..63 convert moebius->fp8 + write-once colsum
// partials; blocks 64..4159 do BCE (fp32-exact) + pred->fp8 (k-interleaved)
// + ws zeroing, 4 rows per block (all 8 P/T float4 + 4 tidx loads in flight
// before compute; product-of-4 logf).
__global__ __launch_bounds__(256)
void bce_convert_kernel(const float* __restrict__ pred,
                        const float* __restrict__ membership,
                        const int*   __restrict__ tidx,
                        const float* __restrict__ moeb,
                        float*       __restrict__ ws,
                        int*         __restrict__ pred_f8,
                        int*         __restrict__ moeb_f8) {
    const int tid = threadIdx.x;
    const int id  = blockIdx.x;
    if (id < 64) {      // moebius: block j handles rows j*16 .. j*16+15
        const int j    = id;
        const int base = j * 4096 + tid;
        float4 csum = make_float4(0.f, 0.f, 0.f, 0.f);
        #pragma unroll
        for (int k = 0; k < 16; k++) {
            const int i = base + k * 256;        // row j*16+k, col4 = tid
            const float4 v = ((const float4*)moeb)[i];
            const int row = i >> 8;
            moeb_f8[(row << 8) | permute_dword(i & 255)] =
                pk_fp8x4(v.x, v.y, v.z, v.w);
            csum.x += v.x; csum.y += v.y; csum.z += v.z; csum.w += v.w;
        }
        ((float4*)(ws + CPART_OFF))[j * 256 + tid] = csum;  // write-once
        return;
    }
    const int bi = id - 64;                   // 0..4095, 4 rows each
    // zero accumulators for the masses kernel (stream order guarantees vis.)
    if (tid < 4)                    ws[ROWSUM_OFF + bi * 4 + tid] = 0.0f;
    if (bi == 0 && tid >= 4 && tid < 8)  ws[tid - 4] = 0.0f;
    if (bi == 1 && tid < NSTRIPE)   ws[STRIPE_OFF + tid] = 0.0f;

    __shared__ float sm[4];
    const float eps = 1e-7f;
    const float hi  = 1.0f - 1e-7f;
    const int   pd  = permute_dword(tid);     // hoisted: same for all rows
    float acc = 0.0f;

    float4 P[4], T[4];
    int rows[4];
    // issue all 4 pred loads
    #pragma unroll
    for (int k = 0; k < 4; k++) {
        rows[k] = bi + k * 4096;
        P[k] = ((const float4*)pred)[rows[k] * 256 + tid];
    }
    // issue all 4 membership gathers (cls is block-uniform -> s_load)
    #pragma unroll
    for (int k = 0; k < 4; k++) {
        const int cls = tidx[rows[k]];
        T[k] = ((const float4*)membership)[(cls << 8) + tid];
    }
    // compute + fp8 store; 1 logf per 4 elements (product in [1e-28,1]:
    // always fp32-normal, unconditionally safe)
    #pragma unroll
    for (int k = 0; k < 4; k++) {
        float cp[4];
        cp[0] = fminf(fmaxf(P[k].x, eps), hi);
        cp[1] = fminf(fmaxf(P[k].y, eps), hi);
        cp[2] = fminf(fmaxf(P[k].z, eps), hi);
        cp[3] = fminf(fmaxf(P[k].w, eps), hi);
        pred_f8[(rows[k] << 8) | pd] = pk_fp8x4(cp[0], cp[1], cp[2], cp[3]);
        const float x0 = (T[k].x > 0.5f) ? cp[0] : (1.0f - cp[0]);
        const float x1 = (T[k].y > 0.5f) ? cp[1] : (1.0f - cp[1]);
        const float x2 = (T[k].z > 0.5f) ? cp[2] : (1.0f - cp[2]);
        const float x3 = (T[k].w > 0.5f) ? cp[3] : (1.0f - cp[3]);
        acc += __logf((x0 * x1) * (x2 * x3));
    }
    const float tot = block_reduce_sum(acc, sm);
    if (tid == 0) ws[BCEP_OFF + bi] = tot;    // write-once partial
}

// -------- k2 (R13/R10 proven, verbatim): masses = p_fp8 @ moeb_fp8^T via
// MFMA for mr; distributed exact fp32 rowsum partials for ms (inline
// epilogue, 64 KB A32 per block -- FREE, overlaps co-resident blocks' MFMA);
// stripe-last folds; global-last finalizes. Double-buffered LDS; fence-free
// counter protocol; XCD swizzle.
__global__ __launch_bounds__(256)
void masses_mfma_kernel(const unsigned char* __restrict__ A,   // pred_fp8
                        const unsigned char* __restrict__ Bm,  // moeb_fp8
                        const float* __restrict__ A32,         // pred fp32
                        float* __restrict__ ws,
                        float* __restrict__ out) {
    __shared__ __align__(16) unsigned char Alds[2][BM * BK];  // 2 x 16 KB
    __shared__ __align__(16) unsigned char Blds[2][BN * BK];  // 2 x 16 KB
    __shared__ float sm[4];
    __shared__ unsigned flag;

    const int tid  = threadIdx.x;
    const int lane = tid & 63;
    const int w    = tid >> 6;
    const int wm   = w >> 1;
    const int wn   = w & 1;
    const int lr   = lane & 15;
    const int q    = lane >> 4;

    // XCD-aware swizzle (performance heuristic only)
    const int id     = blockIdx.x;
    const int xcd    = id & 7;
    const int slot   = id >> 3;                 // 0..127 within XCD
    const int grp    = slot >> 3;               // 0..15
    const int stripe = xcd * 16 + grp;
    const int nblk   = slot & 7;
    const int m0     = stripe * BM;
    const int n0     = nblk * BN;               // also this block's k-chunk base

    f32x4 acc[4][4];
    #pragma unroll
    for (int i = 0; i < 4; i++)
        #pragma unroll
        for (int j = 0; j < 4; j++) acc[i][j] = (f32x4){0.f, 0.f, 0.f, 0.f};

    // staging: 1024 slots of 16B per 16KB tile; thread t covers slots
    // s = t + j*256; slot s -> row r = s>>3, 16B-chunk c = s&7 holds global
    // chunk c ^ (r&7)  (fp8 row = 128 B = BK)
    size_t aoff[4], boff[4];
    unsigned loff[4];
    #pragma unroll
    for (int j = 0; j < 4; j++) {
        const int s  = tid + j * 256;
        const int r  = s >> 3;
        const int gc = (s & 7) ^ (r & 7);
        aoff[j] = (size_t)(m0 + r) * NSETS + gc * 16;
        boff[j] = (size_t)(n0 + r) * NSETS + gc * 16;
        loff[j] = (unsigned)(s * 16);
    }
    const int sw = lr & 7;  // fragment-read swizzle term

    // prologue: issue stage of tile 0 into buffer 0
    #pragma unroll
    for (int j = 0; j < 4; j++) {
        gld16(A  + aoff[j], &Alds[0][loff[j]]);
        gld16(Bm + boff[j], &Blds[0][loff[j]]);
    }

    for (int it = 0; it < KITER; it++) {
        const int cur = it & 1;
        __syncthreads();   // drains vmcnt -> buf[cur] ready; WAR-safe for nxt
        if (it + 1 < KITER) {   // issue next tile: in flight during the MFMAs
            const int nk = (it + 1) * BK;
            #pragma unroll
            for (int j = 0; j < 4; j++) {
                gld16(A  + aoff[j] + nk, &Alds[cur ^ 1][loff[j]]);
                gld16(Bm + boff[j] + nk, &Blds[cur ^ 1][loff[j]]);
            }
        }
        // compute on buf[cur]: b128 reads give 2 MFMA k-steps per fragment
        #pragma unroll
        for (int H = 0; H < 2; H++) {
            const int off = 16 * ((4 * H + q) ^ sw);
            s64x2 a[4], b[4];
            #pragma unroll
            for (int mi = 0; mi < 4; mi++)
                a[mi] = *(const s64x2*)&Alds[cur][(wm * 64 + mi * 16 + lr) * BK + off];
            #pragma unroll
            for (int ni = 0; ni < 4; ni++)
                b[ni] = *(const s64x2*)&Blds[cur][(wn * 64 + ni * 16 + lr) * BK + off];
            #pragma unroll
            for (int mi = 0; mi < 4; mi++)
                #pragma unroll
                for (int ni = 0; ni < 4; ni++) {
                    acc[mi][ni] = __builtin_amdgcn_mfma_f32_16x16x32_fp8_fp8(
                        a[mi][0], b[ni][0], acc[mi][ni], 0, 0, 0);
                    acc[mi][ni] = __builtin_amdgcn_mfma_f32_16x16x32_fp8_fp8(
                        a[mi][1], b[ni][1], acc[mi][ni], 0, 0, 0);
                }
        }
    }

    // ---- mr epilogue ----
    float mrpart = 0.0f;
    #pragma unroll
    for (int mi = 0; mi < 4; mi++)
        #pragma unroll
        for (int ni = 0; ni < 4; ni++)
            #pragma unroll
            for (int r = 0; r < 4; r++)
                mrpart += fmaxf(-acc[mi][ni][r], 0.0f);
    const float mrtot = block_reduce_sum(mrpart, sm);  // has a barrier inside
    if (tid == 0) atomicAdd(&ws[0], mrtot);            // device-scope atomic

    // ---- distributed exact fp32 rowsum partial: k-chunk [n0, n0+128) ----
    __syncthreads();                 // all MFMA reads done -> Alds reusable
    float* clds = (float*)Alds;      // [0..1024) seg partials, [1024..1152) c
    {
        const int col = tid & 31;    // f4-col within the 128-float chunk
        const int seg = tid >> 5;    // 8 segments of 8 c_part rows each
        float4 cs = make_float4(0.f, 0.f, 0.f, 0.f);
        #pragma unroll
        for (int j = 0; j < 8; j++) {   // prev-dispatch data: plain loads OK
            const float4 v = ((const float4*)(ws + CPART_OFF))
                                 [(seg * 8 + j) * 256 + (n0 >> 2) + col];
            cs.x += v.x; cs.y += v.y; cs.z += v.z; cs.w += v.w;
        }
        ((float4*)clds)[seg * 32 + col] = cs;
    }
    __syncthreads();
    if (tid < 32) {
        float4 t = make_float4(0.f, 0.f, 0.f, 0.f);
        #pragma unroll
        for (int s2 = 0; s2 < 8; s2++) {
            const float4 v = ((const float4*)clds)[s2 * 32 + tid];
            t.x += v.x; t.y += v.y; t.z += v.z; t.w += v.w;
        }
        ((float4*)clds)[256 + tid] = t;   // final c chunk at floats [1024..)
    }
    __syncthreads();
    {
        const float eps = 1e-7f;
        const float hi  = 1.0f - 1e-7f;
        const int r    = tid >> 1;        // row within stripe
        const int half = tid & 1;         // 64 k each
        const float4* prow = (const float4*)(A32 + (size_t)(m0 + r) * NSETS
                                             + n0 + half * 64);
        const float4* crow = (const float4*)(clds + 1024 + half * 64);
        float s = 0.0f;
        #pragma unroll
        for (int k = 0; k < 16; k++) {
            float4 pv = prow[k];
            const float4 cv = crow[k];
            pv.x = fminf(fmaxf(pv.x, eps), hi);
            pv.y = fminf(fmaxf(pv.y, eps), hi);
            pv.z = fminf(fmaxf(pv.z, eps), hi);
            pv.w = fminf(fmaxf(pv.w, eps), hi);
            s += pv.x * cv.x + pv.y * cv.y + pv.z * cv.z + pv.w * cv.w;
        }
        s += __shfl_xor(s, 1, 64);        // combine the two k-halves
        if (half == 0) atomicAdd(&ws[ROWSUM_OFF + m0 + r], s);
    }

    // ---- stripe-last: fold |rowsum-1| (fence-free counter protocol) ----
    __syncthreads();   // drains each wave's vmcnt -> atomics at coherent point
    if (tid == 0)
        flag = (__hip_atomic_fetch_add((unsigned int*)&ws[STRIPE_OFF + stripe],
                    1u, __ATOMIC_RELAXED, __HIP_MEMORY_SCOPE_AGENT)
                == NBLK_N - 1);
    __syncthreads();
    if (flag) {
        float sms = 0.0f;
        if (tid < BM)
            sms = fabsf(coh_load(ws + ROWSUM_OFF + m0 + tid) - 1.0f);
        __syncthreads();                 // sm reuse guard
        const float mssum = block_reduce_sum(sms, sm);
        if (tid == 0) atomicAdd(&ws[2], mssum);
    }
    __syncthreads();   // drain the ms atomic before the global bump

    // ---- global-last finalize ----
    if (tid == 0)
        flag = (__hip_atomic_fetch_add((unsigned int*)&ws[1], 1u,
                    __ATOMIC_RELAXED, __HIP_MEMORY_SCOPE_AGENT)
                == GEMM_BLOCKS - 1);
    __syncthreads();
    if (flag) {
        float s_bce = 0.0f;
        #pragma unroll
        for (int k = 0; k < 4; k++) {    // prev-dispatch data: plain loads OK
            const float4 v = ((const float4*)(ws + BCEP_OFF))[tid + k * 256];
            s_bce += v.x + v.y + v.z + v.w;
        }
        __syncthreads();                 // sm reuse guard
        const float bcesum = block_reduce_sum(s_bce, sm);
        if (tid == 0) {
            const float inv = 1.0f / ((float)BATCH * (float)NSETS);
            const float bce = -bcesum * inv;
            const float mr  =  coh_load(ws + 0) * inv;
            const float ms  =  coh_load(ws + 2) / (float)BATCH;
            out[0] = bce + ALPHA * mr + BETA * ms;
            out[1] = bce;
            out[2] = mr;
            out[3] = ms;
        }
    }
}

extern "C" void kernel_launch(void* const* d_in, const int* in_sizes, int n_in,
                              void* d_out, int out_size, void* d_ws, size_t ws_size,
                              hipStream_t stream) {
    const float* pred       = (const float*)d_in[0];
    const float* membership = (const float*)d_in[1];
    const float* moebius    = (const float*)d_in[2];
    const int*   tidx       = (const int*)d_in[3];
    float* out = (float*)d_out;
    float* ws  = (float*)d_ws;
    int* pred_f8 = (int*)((char*)d_ws + WS_PREDF8_OFF);
    int* moeb_f8 = (int*)((char*)d_ws + WS_MOEBF8_OFF);

    bce_convert_kernel<<<K1_GRID, 256, 0, stream>>>(
        pred, membership, tidx, moebius, ws, pred_f8, moeb_f8);
    masses_mfma_kernel<<<GEMM_BLOCKS, 256, 0, stream>>>(
        (const unsigned char*)pred_f8, (const unsigned char*)moeb_f8,
        pred, ws, out);
}